// Round 1
// baseline (443.549 us; speedup 1.0000x reference)
//
#include <hip/hip_runtime.h>
#include <hip/hip_bf16.h>

// Problem constants
#define DL 1024
#define DS 768
#define RK 64
#define GM 16384   // BATCH*SEQ
#define GN 3072    // 3*DL
#define GK 1024    // DL

// GEMM tile: 256x256, BK=64, 512 threads (8 waves as 2Mx4N, each 128x64 output)
#define BM 256
#define BN 256
#define BK 64
#define NTK (GK / BK)   // 16 K-tiles

typedef __attribute__((ext_vector_type(8))) short bf16x8;
typedef __attribute__((ext_vector_type(4))) float f32x4;

__device__ __forceinline__ unsigned short f2bf(float f) {
    union { float f; unsigned int u; } v; v.f = f;
    unsigned int r = v.u + 0x7fffu + ((v.u >> 16) & 1u);  // RNE
    return (unsigned short)(r >> 16);
}

// ---------------------------------------------------------------- x -> bf16
__global__ void cvt_kernel(const float* __restrict__ x, unsigned short* __restrict__ xb, int n4) {
    int i = blockIdx.x * 256 + threadIdx.x;
    if (i < n4) {
        float4 v = ((const float4*)x)[i];
        ushort4 o;
        o.x = f2bf(v.x); o.y = f2bf(v.y); o.z = f2bf(v.z); o.w = f2bf(v.w);
        ((ushort4*)xb)[i] = o;
    }
}

// ------------------------------------------- T1[k][r][t] = sum_s B[k][r][s] * Ws[k][s][t]
__global__ void t1_kernel(const float* __restrict__ W, const float* __restrict__ B,
                          float* __restrict__ T1) {
    __shared__ float Bsh[8 * DS];          // 24 KB
    int t  = blockIdx.x * 256 + threadIdx.x;
    int r0 = blockIdx.y * 8;
    int k  = blockIdx.z;
    const float* Wk = W + (size_t)k * DS * DS;
    const float* Bk = B + ((size_t)k * RK + r0) * DS;
    for (int i = threadIdx.x; i < 8 * DS; i += 256) Bsh[i] = Bk[i];
    __syncthreads();
    float acc[8];
#pragma unroll
    for (int j = 0; j < 8; ++j) acc[j] = 0.f;
    for (int s = 0; s < DS; ++s) {
        float ws = Wk[(size_t)s * DS + t];
#pragma unroll
        for (int j = 0; j < 8; ++j) acc[j] += Bsh[j * DS + s] * ws;
    }
#pragma unroll
    for (int j = 0; j < 8; ++j)
        T1[((size_t)k * RK + (r0 + j)) * DS + t] = acc[j];
}

// ------------------------------------------- M[k][r][q] = sum_t T1[k][r][t] * B[k][q][t]
__global__ void m_kernel(const float* __restrict__ T1, const float* __restrict__ B,
                         float* __restrict__ Mm) {
    int w = blockIdx.x * 4 + (threadIdx.x >> 6);
    int lane = threadIdx.x & 63;
    int k = w / (RK * RK);
    int rem = w % (RK * RK);
    int r = rem / RK, q = rem % RK;
    const float* t1 = T1 + ((size_t)k * RK + r) * DS;
    const float* bq = B  + ((size_t)k * RK + q) * DS;
    float acc = 0.f;
    for (int t = lane; t < DS; t += 64) acc += t1[t] * bq[t];
#pragma unroll
    for (int off = 32; off > 0; off >>= 1) acc += __shfl_xor(acc, off, 64);
    if (lane == 0) Mm[w] = acc;
}

// ------------------------------------------- U[k][e][q] = sum_r A[k][e][r] * M[k][r][q]
__global__ void u_kernel(const float* __restrict__ A, const float* __restrict__ Mm,
                         float* __restrict__ U) {
    int q  = threadIdx.x & 63;
    int el = threadIdx.x >> 6;
    int k  = blockIdx.x / 256;
    int e  = (blockIdx.x % 256) * 4 + el;
    const float* Ae = A  + ((size_t)k * DL + e) * RK;
    const float* Mk = Mm + (size_t)k * RK * RK;
    float acc = 0.f;
#pragma unroll
    for (int r = 0; r < RK; ++r) acc += Ae[r] * Mk[r * RK + q];
    U[((size_t)k * DL + e) * RK + q] = acc;
}

// ------------------------------------------- At[k][q][d] = A[k][d][q]
__global__ void at_kernel(const float* __restrict__ A, float* __restrict__ At) {
    int i = blockIdx.x * 256 + threadIdx.x;     // i = (k*RK + q)*DL + d
    int d = i % DL;
    int kq = i / DL;
    int q = kq % RK, k = kq / RK;
    At[i] = A[((size_t)k * DL + d) * RK + q];
}

// ------------------------------------------- Wc[k*DL+e][d] = bf16( sum_q U[k][e][q]*At[k][q][d] )
__global__ void wcat_kernel(const float* __restrict__ U, const float* __restrict__ At,
                            unsigned short* __restrict__ Wc) {
    __shared__ float Ush[8 * RK];          // 2 KB
    int d  = (blockIdx.x & 3) * 256 + threadIdx.x;
    int e0 = ((blockIdx.x >> 2) & 127) * 8;
    int k  = blockIdx.x >> 9;
    const float* Uk  = U  + ((size_t)k * DL + e0) * RK;
    const float* Atk = At + (size_t)k * RK * DL;
    for (int i = threadIdx.x; i < 8 * RK; i += 256) Ush[i] = Uk[i];
    __syncthreads();
    float acc[8];
#pragma unroll
    for (int j = 0; j < 8; ++j) acc[j] = 0.f;
    for (int q = 0; q < RK; ++q) {
        float a = Atk[(size_t)q * DL + d];
#pragma unroll
        for (int j = 0; j < 8; ++j) acc[j] += Ush[j * RK + q] * a;
    }
#pragma unroll
    for (int j = 0; j < 8; ++j)
        Wc[((size_t)k * DL + (e0 + j)) * GK + d] = f2bf(acc[j]);
}

// ------------------------------------------- main GEMM: C[M,N] = Xb[M,K] * Wc[N,K]^T
// 256x256 tile, 8-phase schedule (T2 swizzle + T3/T4 counted vmcnt + T5 setprio).
// LDS: 2 K-tile buffers x (A 256x64 + B 256x64), each operand split in two
// 128x64 halves -> 128 KiB. Tile parity fixes buffers: even tiles buf0, odd buf1.
// Wave (wm,wn) owns rows {mh*128 + wm*64 + mi*16} x cols {nh*128 + wn*32 + ni*16},
// so quadrant (mh,nh) touches exactly halves A[mh], B[nh] -> each half is free
// for prefetch right after its last reading phase. vmcnt(4) at phases 4/8 only:
// 2 half-tiles (4 loads) stay in flight across every wait; never drained to 0
// in the steady state.
// XOR swizzle: LDS slot (row, cs) holds global k-chunk cs^(row&7); readers XOR
// the same way -> ds_read_b128 is 2-way max (free).

#define ASL(B_, H_) (((B_) * 2 + (H_)) * 8192)
#define BSL(B_, H_) (32768 + ((B_) * 2 + (H_)) * 8192)

#define BAR()                                   \
    do {                                        \
        __builtin_amdgcn_sched_barrier(0);      \
        __builtin_amdgcn_s_barrier();           \
        __builtin_amdgcn_sched_barrier(0);      \
    } while (0)

#define STAGE(GB, T_, H_, SL)                                                               \
    do {                                                                                    \
        _Pragma("unroll")                                                                   \
        for (int l = 0; l < 2; ++l)                                                         \
            __builtin_amdgcn_global_load_lds(                                               \
                (const __attribute__((address_space(1))) void*)(                            \
                    (GB) + (size_t)(H_) * 128 * GK + (size_t)(T_) * BK + srcoff[l]),        \
                (__attribute__((address_space(3))) void*)(sh + (SL) + dstoff[l]),           \
                16, 0, 0);                                                                  \
    } while (0)

#define LDA(B_, H_)                                                                         \
    do {                                                                                    \
        _Pragma("unroll")                                                                   \
        for (int mi = 0; mi < 4; ++mi) {                                                    \
            const int lr = lrA + mi * 16;                                                   \
            _Pragma("unroll")                                                               \
            for (int kk = 0; kk < 2; ++kk)                                                  \
                af[mi][kk] = *(const bf16x8*)(sh + ASL(B_, H_) + lr * 64 +                  \
                                              (((kk * 4 + cq) ^ (lr & 7)) * 8));            \
        }                                                                                   \
    } while (0)

#define LDB(B_, H_)                                                                         \
    do {                                                                                    \
        _Pragma("unroll")                                                                   \
        for (int ni = 0; ni < 2; ++ni) {                                                    \
            const int lr = lrB + ni * 16;                                                   \
            _Pragma("unroll")                                                               \
            for (int kk = 0; kk < 2; ++kk)                                                  \
                bfr[ni][kk] = *(const bf16x8*)(sh + BSL(B_, H_) + lr * 64 +                 \
                                               (((kk * 4 + cq) ^ (lr & 7)) * 8));           \
        }                                                                                   \
    } while (0)

#define QUAD(MH_, NH_)                                                                      \
    do {                                                                                    \
        __builtin_amdgcn_s_setprio(1);                                                      \
        _Pragma("unroll")                                                                   \
        for (int kk = 0; kk < 2; ++kk)                                                      \
            _Pragma("unroll")                                                               \
            for (int mi = 0; mi < 4; ++mi)                                                  \
                _Pragma("unroll")                                                           \
                for (int ni = 0; ni < 2; ++ni)                                              \
                    acc[(MH_) * 4 + mi][(NH_) * 2 + ni] =                                   \
                        __builtin_amdgcn_mfma_f32_16x16x32_bf16(                            \
                            af[mi][kk], bfr[ni][kk],                                        \
                            acc[(MH_) * 4 + mi][(NH_) * 2 + ni], 0, 0, 0);                  \
        __builtin_amdgcn_s_setprio(0);                                                      \
    } while (0)

__global__ __launch_bounds__(512, 2) void gemm_kernel(const unsigned short* __restrict__ Ag,
                                                      const unsigned short* __restrict__ Bg,
                                                      float* __restrict__ C) {
    __shared__ unsigned short sh[65536];   // 128 KiB

    const int tid  = threadIdx.x;
    const int lane = tid & 63;
    const int wave = tid >> 6;
    const int wm = wave >> 2;        // 0..1
    const int wn = wave & 3;         // 0..3

    // XCD-bijective swizzle (768 % 8 == 0)
    const int bid = blockIdx.x;
    const int wg  = (bid & 7) * ((int)gridDim.x >> 3) + (bid >> 3);
    const int bn0 = (wg % (GN / BN)) * BN;
    const int bm0 = (wg / (GN / BN)) * BM;

    // fragment read coords (16x16x32 layout: row = lane&15, k-chunk = lane>>4)
    const int rr  = lane & 15;
    const int cq  = lane >> 4;           // 0..3
    const int lrA = wm * 64 + rr;        // + mi*16 : local row within A-half
    const int lrB = wn * 32 + rr;        // + ni*16 : local row within B-half

    // staging coords: chunk c = l*512+tid of a 128x64 half (16 KB)
    int srcoff[2], dstoff[2];
#pragma unroll
    for (int l = 0; l < 2; ++l) {
        const int c = l * 512 + tid;
        const int r = c >> 3, cs = c & 7;
        srcoff[l] = r * GK + ((cs ^ (r & 7)) * 8);   // element offset (pre-inverse-swizzled source)
        dstoff[l] = c * 8;                           // linear LDS dest (shorts)
    }

    const unsigned short* Abase = Ag + (size_t)bm0 * GK;
    const unsigned short* Bbase = Bg + (size_t)bn0 * GK;

    f32x4 acc[8][4];
#pragma unroll
    for (int i = 0; i < 8; ++i)
#pragma unroll
        for (int j = 0; j < 4; ++j) {
            f32x4 z = {0.f, 0.f, 0.f, 0.f};
            acc[i][j] = z;
        }
    bf16x8 af[4][2], bfr[2][2];

    // Prologue: tile0 complete + tile1 A0,B0; leave t1A0,t1B0 (4 loads) in flight
    STAGE(Abase, 0, 0, ASL(0, 0));
    STAGE(Bbase, 0, 0, BSL(0, 0));
    STAGE(Abase, 0, 1, ASL(0, 1));
    STAGE(Bbase, 0, 1, BSL(0, 1));
    STAGE(Abase, 1, 0, ASL(1, 0));
    STAGE(Bbase, 1, 0, BSL(1, 0));
    asm volatile("s_waitcnt vmcnt(4)");
    BAR();

    for (int ti = 0; ti < NTK; ti += 2) {
        const bool more = (ti + 2) < NTK;

        // P1: buf0 quad(0,0); stage (ti+1)A1
        LDA(0, 0); LDB(0, 0);
        STAGE(Abase, ti + 1, 1, ASL(1, 1));
        BAR();
        QUAD(0, 0);
        BAR();

        // P2: buf0 quad(0,1) (reuse af); stage (ti+1)B1
        LDB(0, 1);
        STAGE(Bbase, ti + 1, 1, BSL(1, 1));
        BAR();
        QUAD(0, 1);
        BAR();

        // P3: buf0 quad(1,0); stage (ti+2)A0 over buf0.A0 (last read P1)
        LDA(0, 1); LDB(0, 0);
        if (more) STAGE(Abase, ti + 2, 0, ASL(0, 0));
        BAR();
        QUAD(1, 0);
        BAR();

        // P4: buf0 quad(1,1); stage (ti+2)B0; counted wait
        LDB(0, 1);
        if (more) STAGE(Bbase, ti + 2, 0, BSL(0, 0));
        BAR();
        QUAD(1, 1);
        if (more) asm volatile("s_waitcnt vmcnt(4)");
        else      asm volatile("s_waitcnt vmcnt(0)");   // tail: t(i+1)A1/B1 must land
        BAR();

        // P5: buf1 quad(0,0); stage (ti+2)A1 over buf0.A1 (last read P3)
        LDA(1, 0); LDB(1, 0);
        if (more) STAGE(Abase, ti + 2, 1, ASL(0, 1));
        BAR();
        QUAD(0, 0);
        BAR();

        // P6: buf1 quad(0,1); stage (ti+2)B1 over buf0.B1 (last read P4)
        LDB(1, 1);
        if (more) STAGE(Bbase, ti + 2, 1, BSL(0, 1));
        BAR();
        QUAD(0, 1);
        BAR();

        // P7: buf1 quad(1,0); stage (ti+3)A0 over buf1.A0 (last read P5)
        LDA(1, 1); LDB(1, 0);
        if (more) STAGE(Abase, ti + 3, 0, ASL(1, 0));
        BAR();
        QUAD(1, 0);
        BAR();

        // P8: buf1 quad(1,1); stage (ti+3)B0 over buf1.B0 (last read P7); counted wait
        LDB(1, 1);
        if (more) STAGE(Bbase, ti + 3, 0, BSL(1, 0));
        BAR();
        QUAD(1, 1);
        if (more) asm volatile("s_waitcnt vmcnt(4)");
        BAR();
    }

    // epilogue: D layout col=lane&15, row=(lane>>4)*4+reg
    const int cn  = lane & 15;
    const int rg4 = (lane >> 4) * 4;
#pragma unroll
    for (int m = 0; m < 8; ++m) {
        const int mh = m >> 2, mi = m & 3;
        const int row0 = bm0 + mh * 128 + wm * 64 + mi * 16 + rg4;
#pragma unroll
        for (int n = 0; n < 4; ++n) {
            const int nh = n >> 1, ni = n & 1;
            const int col = bn0 + nh * 128 + wn * 32 + ni * 16 + cn;
#pragma unroll
            for (int r = 0; r < 4; ++r)
                C[(size_t)(row0 + r) * GN + col] = acc[m][n][r];
        }
    }
}

extern "C" void kernel_launch(void* const* d_in, const int* in_sizes, int n_in,
                              void* d_out, int out_size, void* d_ws, size_t ws_size,
                              hipStream_t stream) {
    const float* x   = (const float*)d_in[0];
    const float* Wsm = (const float*)d_in[1];
    const float* A   = (const float*)d_in[2];
    const float* B   = (const float*)d_in[3];
    float* out = (float*)d_out;
    char* ws = (char*)d_ws;

    unsigned short* xb = (unsigned short*)(ws);                       // 33,554,432 B
    unsigned short* Wc = (unsigned short*)(ws + 33554432);            //  6,291,456 B
    float* T1          = (float*)(ws + 39845888);                     //    589,824 B
    float* Mm          = (float*)(ws + 40435712);                     //     49,152 B
    float* U           = (float*)(ws + 40484864);                     //    786,432 B
    float* At          = (float*)(ws + 41271296);                     //    786,432 B

    cvt_kernel<<<GM * GK / 4 / 256, 256, 0, stream>>>(x, xb, GM * GK / 4);
    t1_kernel<<<dim3(3, 8, 3), 256, 0, stream>>>(Wsm, B, T1);
    m_kernel<<<3 * RK * RK / 4, 256, 0, stream>>>(T1, B, Mm);
    u_kernel<<<3 * DL / 4, 256, 0, stream>>>(A, Mm, U);
    at_kernel<<<3 * RK * DL / 256, 256, 0, stream>>>(A, At);
    wcat_kernel<<<1536, 256, 0, stream>>>(U, At, Wc);
    gemm_kernel<<<(GM / BM) * (GN / BN), 512, 0, stream>>>(xb, Wc, out);
}

// Round 2
// 435.493 us; speedup vs baseline: 1.0185x; 1.0185x over previous
//
#include <hip/hip_runtime.h>
#include <hip/hip_bf16.h>

// Problem constants
#define DL 1024
#define DS 768
#define RK 64
#define GM 16384   // BATCH*SEQ
#define GN 3072    // 3*DL
#define GK 1024    // DL

// GEMM tile: 256x256, BK=64, 512 threads (8 waves as 2Mx4N, each 128x64 output)
#define BM 256
#define BN 256
#define BK 64
#define NTK (GK / BK)   // 16 K-tiles

typedef __attribute__((ext_vector_type(8))) short bf16x8;
typedef __attribute__((ext_vector_type(4))) float f32x4;

__device__ __forceinline__ unsigned short f2bf(float f) {
    union { float f; unsigned int u; } v; v.f = f;
    unsigned int r = v.u + 0x7fffu + ((v.u >> 16) & 1u);  // RNE
    return (unsigned short)(r >> 16);
}

// ---------------------------------------------------------------- x -> bf16
__global__ void cvt_kernel(const float* __restrict__ x, unsigned short* __restrict__ xb, int n4) {
    int i = blockIdx.x * 256 + threadIdx.x;
    if (i < n4) {
        float4 v = ((const float4*)x)[i];
        ushort4 o;
        o.x = f2bf(v.x); o.y = f2bf(v.y); o.z = f2bf(v.z); o.w = f2bf(v.w);
        ((ushort4*)xb)[i] = o;
    }
}

// ------------------------------------------- T1[k][r][t] = sum_s B[k][r][s] * Ws[k][s][t]
__global__ void t1_kernel(const float* __restrict__ W, const float* __restrict__ B,
                          float* __restrict__ T1) {
    __shared__ float Bsh[8 * DS];          // 24 KB
    int t  = blockIdx.x * 256 + threadIdx.x;
    int r0 = blockIdx.y * 8;
    int k  = blockIdx.z;
    const float* Wk = W + (size_t)k * DS * DS;
    const float* Bk = B + ((size_t)k * RK + r0) * DS;
    for (int i = threadIdx.x; i < 8 * DS; i += 256) Bsh[i] = Bk[i];
    __syncthreads();
    float acc[8];
#pragma unroll
    for (int j = 0; j < 8; ++j) acc[j] = 0.f;
    for (int s = 0; s < DS; ++s) {
        float ws = Wk[(size_t)s * DS + t];
#pragma unroll
        for (int j = 0; j < 8; ++j) acc[j] += Bsh[j * DS + s] * ws;
    }
#pragma unroll
    for (int j = 0; j < 8; ++j)
        T1[((size_t)k * RK + (r0 + j)) * DS + t] = acc[j];
}

// ------------------------------------------- M[k][r][q] = sum_t T1[k][r][t] * B[k][q][t]
__global__ void m_kernel(const float* __restrict__ T1, const float* __restrict__ B,
                         float* __restrict__ Mm) {
    int w = blockIdx.x * 4 + (threadIdx.x >> 6);
    int lane = threadIdx.x & 63;
    int k = w / (RK * RK);
    int rem = w % (RK * RK);
    int r = rem / RK, q = rem % RK;
    const float* t1 = T1 + ((size_t)k * RK + r) * DS;
    const float* bq = B  + ((size_t)k * RK + q) * DS;
    float acc = 0.f;
    for (int t = lane; t < DS; t += 64) acc += t1[t] * bq[t];
#pragma unroll
    for (int off = 32; off > 0; off >>= 1) acc += __shfl_xor(acc, off, 64);
    if (lane == 0) Mm[w] = acc;
}

// ------------------------------------------- U[k][e][q] = sum_r A[k][e][r] * M[k][r][q]
__global__ void u_kernel(const float* __restrict__ A, const float* __restrict__ Mm,
                         float* __restrict__ U) {
    int q  = threadIdx.x & 63;
    int el = threadIdx.x >> 6;
    int k  = blockIdx.x / 256;
    int e  = (blockIdx.x % 256) * 4 + el;
    const float* Ae = A  + ((size_t)k * DL + e) * RK;
    const float* Mk = Mm + (size_t)k * RK * RK;
    float acc = 0.f;
#pragma unroll
    for (int r = 0; r < RK; ++r) acc += Ae[r] * Mk[r * RK + q];
    U[((size_t)k * DL + e) * RK + q] = acc;
}

// ------------------------------------------- At[k][q][d] = A[k][d][q]
__global__ void at_kernel(const float* __restrict__ A, float* __restrict__ At) {
    int i = blockIdx.x * 256 + threadIdx.x;     // i = (k*RK + q)*DL + d
    int d = i % DL;
    int kq = i / DL;
    int q = kq % RK, k = kq / RK;
    At[i] = A[((size_t)k * DL + d) * RK + q];
}

// ------------------------------------------- Wc[k*DL+e][d] = bf16( sum_q U[k][e][q]*At[k][q][d] )
__global__ void wcat_kernel(const float* __restrict__ U, const float* __restrict__ At,
                            unsigned short* __restrict__ Wc) {
    __shared__ float Ush[8 * RK];          // 2 KB
    int d  = (blockIdx.x & 3) * 256 + threadIdx.x;
    int e0 = ((blockIdx.x >> 2) & 127) * 8;
    int k  = blockIdx.x >> 9;
    const float* Uk  = U  + ((size_t)k * DL + e0) * RK;
    const float* Atk = At + (size_t)k * RK * DL;
    for (int i = threadIdx.x; i < 8 * RK; i += 256) Ush[i] = Uk[i];
    __syncthreads();
    float acc[8];
#pragma unroll
    for (int j = 0; j < 8; ++j) acc[j] = 0.f;
    for (int q = 0; q < RK; ++q) {
        float a = Atk[(size_t)q * DL + d];
#pragma unroll
        for (int j = 0; j < 8; ++j) acc[j] += Ush[j * RK + q] * a;
    }
#pragma unroll
    for (int j = 0; j < 8; ++j)
        Wc[((size_t)k * DL + (e0 + j)) * GK + d] = f2bf(acc[j]);
}

// ------------------------------------------- main GEMM: C[M,N] = Xb[M,K] * Wc[N,K]^T
// 256x256, 8-phase (T2 swizzle + T3/T4 counted vmcnt + T5 setprio), template-faithful:
// raw s_barrier (NO sched_barrier pinning — m141 lesson), lgkmcnt(0) after the
// pre-MFMA barrier, sched_barrier(0) ONLY after counted vmcnt waits (hoist fence).
// 8 persistent per-lane source pointers; per-phase tile offset (TR*BK, <=384B)
// folds into the load's immediate. Tail iteration peeled (branch-free steady loop).
// Schedule audit (RAW: stage completion before read; WAR: overwrite after last read):
//   P1 rd b0.A0/B0, st t+1.A1->b1 | P2 rd b0.B1, st t+1.B1->b1
//   P3 rd b0.A1/B0, st t+2.A0->b0 | P4 rd b0.B1, st t+2.B0->b0, vmcnt(4)
//   P5 rd b1.A0/B0, st t+2.A1->b0 | P6 rd b1.B1, st t+2.B1->b0
//   P7 rd b1.A1/B0, st t+3.A0->b1 | P8 rd b1.B1, st t+3.B0->b1, vmcnt(4)
// vmcnt(4) leaves exactly the 2 most recent half-tiles (4 loads) in flight.

#define ASL(B_, H_) (((B_) * 2 + (H_)) * 8192)
#define BSL(B_, H_) (32768 + ((B_) * 2 + (H_)) * 8192)

#define BARRIER() __builtin_amdgcn_s_barrier()
#define LGKM0()   asm volatile("s_waitcnt lgkmcnt(0)")
#define VWAIT(N_)                                       \
    do {                                                \
        asm volatile("s_waitcnt vmcnt(" #N_ ")");       \
        __builtin_amdgcn_sched_barrier(0);              \
    } while (0)

#define GLL(SRC, DST)                                                        \
    __builtin_amdgcn_global_load_lds(                                        \
        (const __attribute__((address_space(1))) void*)(SRC),                \
        (__attribute__((address_space(3))) void*)(DST), 16, 0, 0)

#define STG_A(H_, TR_, SL_)                                 \
    do {                                                    \
        GLL(pa##H_##0 + (TR_) * BK, shw + (SL_));           \
        GLL(pa##H_##1 + (TR_) * BK, shw + (SL_) + 4096);    \
    } while (0)

#define STG_B(H_, TR_, SL_)                                 \
    do {                                                    \
        GLL(pb##H_##0 + (TR_) * BK, shw + (SL_));           \
        GLL(pb##H_##1 + (TR_) * BK, shw + (SL_) + 4096);    \
    } while (0)

#define LDA(B_, H_)                                                                         \
    do {                                                                                    \
        _Pragma("unroll")                                                                   \
        for (int mi = 0; mi < 4; ++mi) {                                                    \
            const int lr = lrA + mi * 16;                                                   \
            _Pragma("unroll")                                                               \
            for (int kk = 0; kk < 2; ++kk)                                                  \
                af[mi][kk] = *(const bf16x8*)(sh + ASL(B_, H_) + lr * 64 +                  \
                                              (((kk * 4 + cq) ^ (lr & 7)) * 8));            \
        }                                                                                   \
    } while (0)

#define LDB(B_, H_)                                                                         \
    do {                                                                                    \
        _Pragma("unroll")                                                                   \
        for (int ni = 0; ni < 2; ++ni) {                                                    \
            const int lr = lrB + ni * 16;                                                   \
            _Pragma("unroll")                                                               \
            for (int kk = 0; kk < 2; ++kk)                                                  \
                bfr[ni][kk] = *(const bf16x8*)(sh + BSL(B_, H_) + lr * 64 +                 \
                                               (((kk * 4 + cq) ^ (lr & 7)) * 8));           \
        }                                                                                   \
    } while (0)

#define QUAD(MH_, NH_)                                                                      \
    do {                                                                                    \
        __builtin_amdgcn_s_setprio(1);                                                      \
        _Pragma("unroll")                                                                   \
        for (int kk = 0; kk < 2; ++kk)                                                      \
            _Pragma("unroll")                                                               \
            for (int mi = 0; mi < 4; ++mi)                                                  \
                _Pragma("unroll")                                                           \
                for (int ni = 0; ni < 2; ++ni)                                              \
                    acc[(MH_) * 4 + mi][(NH_) * 2 + ni] =                                   \
                        __builtin_amdgcn_mfma_f32_16x16x32_bf16(                            \
                            af[mi][kk], bfr[ni][kk],                                        \
                            acc[(MH_) * 4 + mi][(NH_) * 2 + ni], 0, 0, 0);                  \
        __builtin_amdgcn_s_setprio(0);                                                      \
    } while (0)

__global__ __launch_bounds__(512, 2) void gemm_kernel(const unsigned short* __restrict__ Ag,
                                                      const unsigned short* __restrict__ Bg,
                                                      float* __restrict__ C) {
    __shared__ unsigned short sh[65536];   // 128 KiB

    const int tid  = threadIdx.x;
    const int lane = tid & 63;
    const int wave = tid >> 6;
    const int wm = wave >> 2;        // 0..1
    const int wn = wave & 3;         // 0..3

    // XCD-bijective swizzle (768 % 8 == 0)
    const int bid = blockIdx.x;
    const int wg  = (bid & 7) * ((int)gridDim.x >> 3) + (bid >> 3);
    const int bn0 = (wg % (GN / BN)) * BN;
    const int bm0 = (wg / (GN / BN)) * BM;

    // fragment read coords (16x16x32 layout: row = lane&15, k-chunk = lane>>4)
    const int rr  = lane & 15;
    const int cq  = lane >> 4;           // 0..3
    const int lrA = wm * 64 + rr;        // + mi*16 : local row within A-half
    const int lrB = wn * 32 + rr;        // + ni*16 : local row within B-half

    // per-lane source offset within a 128x64 half (pre-inverse-swizzled):
    // chunk c = l*512 + tid -> row r = c>>3, lds-chunk cs = c&7; since 512%512==0,
    // (r&7) and cs are identical for l=0,1 => l just adds 64 rows.
    const int srow = tid >> 3;           // 0..63
    const int scs  = tid & 7;
    const int soff = srow * GK + ((scs ^ (srow & 7)) * 8);

    const unsigned short* pa00 = Ag + (size_t)bm0 * GK + soff;            // A half0, rows 0-63
    const unsigned short* pa01 = pa00 + (size_t)64 * GK;                  // A half0, rows 64-127
    const unsigned short* pa10 = pa00 + (size_t)128 * GK;                 // A half1, rows 0-63
    const unsigned short* pa11 = pa00 + (size_t)192 * GK;                 // A half1, rows 64-127
    const unsigned short* pb00 = Bg + (size_t)bn0 * GK + soff;
    const unsigned short* pb01 = pb00 + (size_t)64 * GK;
    const unsigned short* pb10 = pb00 + (size_t)128 * GK;
    const unsigned short* pb11 = pb00 + (size_t)192 * GK;

    // wave-uniform LDS dst base: chunk l*512 + wave*64 -> shorts l*4096 + wave*512
    unsigned short* const shw = sh + wave * 512;

    f32x4 acc[8][4];
#pragma unroll
    for (int i = 0; i < 8; ++i)
#pragma unroll
        for (int j = 0; j < 4; ++j) {
            f32x4 z = {0.f, 0.f, 0.f, 0.f};
            acc[i][j] = z;
        }
    bf16x8 af[4][2], bfr[2][2];

    // Prologue: tile0 all 4 halves + tile1 A0,B0; leave tile1 A0,B0 (4 loads) in flight
    STG_A(0, 0, ASL(0, 0));
    STG_B(0, 0, BSL(0, 0));
    STG_A(1, 0, ASL(0, 1));
    STG_B(1, 0, BSL(0, 1));
    STG_A(0, 1, ASL(1, 0));
    STG_B(0, 1, BSL(1, 0));
    VWAIT(4);
    BARRIER();

#pragma unroll 1
    for (int ti = 0; ti < NTK - 2; ti += 2) {
        // P1
        LDA(0, 0); LDB(0, 0); STG_A(1, 1, ASL(1, 1));
        BARRIER(); LGKM0();
        QUAD(0, 0);
        BARRIER();
        // P2 (reuse af)
        LDB(0, 1); STG_B(1, 1, BSL(1, 1));
        BARRIER(); LGKM0();
        QUAD(0, 1);
        BARRIER();
        // P3
        LDA(0, 1); LDB(0, 0); STG_A(0, 2, ASL(0, 0));
        BARRIER(); LGKM0();
        QUAD(1, 0);
        BARRIER();
        // P4
        LDB(0, 1); STG_B(0, 2, BSL(0, 0));
        BARRIER(); LGKM0();
        QUAD(1, 1);
        VWAIT(4);
        BARRIER();
        // P5
        LDA(1, 0); LDB(1, 0); STG_A(1, 2, ASL(0, 1));
        BARRIER(); LGKM0();
        QUAD(0, 0);
        BARRIER();
        // P6
        LDB(1, 1); STG_B(1, 2, BSL(0, 1));
        BARRIER(); LGKM0();
        QUAD(0, 1);
        BARRIER();
        // P7
        LDA(1, 1); LDB(1, 0); STG_A(0, 3, ASL(1, 0));
        BARRIER(); LGKM0();
        QUAD(1, 0);
        BARRIER();
        // P8
        LDB(1, 1); STG_B(0, 3, BSL(1, 0));
        BARRIER(); LGKM0();
        QUAD(1, 1);
        VWAIT(4);
        BARRIER();
        // advance source pointers by 2 K-tiles
        pa00 += 2 * BK; pa01 += 2 * BK; pa10 += 2 * BK; pa11 += 2 * BK;
        pb00 += 2 * BK; pb01 += 2 * BK; pb10 += 2 * BK; pb11 += 2 * BK;
    }

    // Tail (last 2 K-tiles): only tile+1 A1/B1 still need staging; drain at P4.
    // P1
    LDA(0, 0); LDB(0, 0); STG_A(1, 1, ASL(1, 1));
    BARRIER(); LGKM0();
    QUAD(0, 0);
    BARRIER();
    // P2
    LDB(0, 1); STG_B(1, 1, BSL(1, 1));
    BARRIER(); LGKM0();
    QUAD(0, 1);
    BARRIER();
    // P3
    LDA(0, 1); LDB(0, 0);
    BARRIER(); LGKM0();
    QUAD(1, 0);
    BARRIER();
    // P4
    LDB(0, 1);
    BARRIER(); LGKM0();
    QUAD(1, 1);
    VWAIT(0);
    BARRIER();
    // P5
    LDA(1, 0); LDB(1, 0);
    BARRIER(); LGKM0();
    QUAD(0, 0);
    BARRIER();
    // P6
    LDB(1, 1);
    BARRIER(); LGKM0();
    QUAD(0, 1);
    BARRIER();
    // P7
    LDA(1, 1); LDB(1, 0);
    BARRIER(); LGKM0();
    QUAD(1, 0);
    BARRIER();
    // P8
    LDB(1, 1);
    BARRIER(); LGKM0();
    QUAD(1, 1);

    // epilogue: D layout col=lane&15, row=(lane>>4)*4+reg
    const int cn  = lane & 15;
    const int rg4 = (lane >> 4) * 4;
#pragma unroll
    for (int m = 0; m < 8; ++m) {
        const int mh = m >> 2, mi = m & 3;
        const int row0 = bm0 + mh * 128 + wm * 64 + mi * 16 + rg4;
#pragma unroll
        for (int n = 0; n < 4; ++n) {
            const int nh = n >> 1, ni = n & 1;
            const int col = bn0 + nh * 128 + wn * 32 + ni * 16 + cn;
#pragma unroll
            for (int r = 0; r < 4; ++r)
                C[(size_t)(row0 + r) * GN + col] = acc[m][n][r];
        }
    }
}

extern "C" void kernel_launch(void* const* d_in, const int* in_sizes, int n_in,
                              void* d_out, int out_size, void* d_ws, size_t ws_size,
                              hipStream_t stream) {
    const float* x   = (const float*)d_in[0];
    const float* Wsm = (const float*)d_in[1];
    const float* A   = (const float*)d_in[2];
    const float* B   = (const float*)d_in[3];
    float* out = (float*)d_out;
    char* ws = (char*)d_ws;

    unsigned short* xb = (unsigned short*)(ws);                       // 33,554,432 B
    unsigned short* Wc = (unsigned short*)(ws + 33554432);            //  6,291,456 B
    float* T1          = (float*)(ws + 39845888);                     //    589,824 B
    float* Mm          = (float*)(ws + 40435712);                     //     49,152 B
    float* U           = (float*)(ws + 40484864);                     //    786,432 B
    float* At          = (float*)(ws + 41271296);                     //    786,432 B

    cvt_kernel<<<GM * GK / 4 / 256, 256, 0, stream>>>(x, xb, GM * GK / 4);
    t1_kernel<<<dim3(3, 8, 3), 256, 0, stream>>>(Wsm, B, T1);
    m_kernel<<<3 * RK * RK / 4, 256, 0, stream>>>(T1, B, Mm);
    u_kernel<<<3 * DL / 4, 256, 0, stream>>>(A, Mm, U);
    at_kernel<<<3 * RK * DL / 256, 256, 0, stream>>>(A, At);
    wcat_kernel<<<1536, 256, 0, stream>>>(U, At, Wc);
    gemm_kernel<<<(GM / BM) * (GN / BN), 512, 0, stream>>>(xb, Wc, out);
}

// Round 3
// 431.788 us; speedup vs baseline: 1.0272x; 1.0086x over previous
//
#include <hip/hip_runtime.h>
#include <hip/hip_bf16.h>

// Problem constants
#define DL 1024
#define DS 768
#define RK 64
#define GM 16384   // BATCH*SEQ
#define GN 3072    // 3*DL
#define GK 1024    // DL

// GEMM tile: 256x256, BK=64, 512 threads (8 waves as 2Mx4N, each 128x64 output)
#define BM 256
#define BN 256
#define BK 64
#define NTK (GK / BK)   // 16 K-tiles

typedef __attribute__((ext_vector_type(8))) short bf16x8;
typedef __attribute__((ext_vector_type(4))) float f32x4;

__device__ __forceinline__ unsigned short f2bf(float f) {
    union { float f; unsigned int u; } v; v.f = f;
    unsigned int r = v.u + 0x7fffu + ((v.u >> 16) & 1u);  // RNE
    return (unsigned short)(r >> 16);
}

// ---------------------------------------------------------------- x -> bf16
__global__ void cvt_kernel(const float* __restrict__ x, unsigned short* __restrict__ xb, int n4) {
    int i = blockIdx.x * 256 + threadIdx.x;
    if (i < n4) {
        float4 v = ((const float4*)x)[i];
        ushort4 o;
        o.x = f2bf(v.x); o.y = f2bf(v.y); o.z = f2bf(v.z); o.w = f2bf(v.w);
        ((ushort4*)xb)[i] = o;
    }
}

// ------------------------------------------- T1[k][r][t] = sum_s B[k][r][s] * Ws[k][s][t]
__global__ void t1_kernel(const float* __restrict__ W, const float* __restrict__ B,
                          float* __restrict__ T1) {
    __shared__ float Bsh[8 * DS];          // 24 KB
    int t  = blockIdx.x * 256 + threadIdx.x;
    int r0 = blockIdx.y * 8;
    int k  = blockIdx.z;
    const float* Wk = W + (size_t)k * DS * DS;
    const float* Bk = B + ((size_t)k * RK + r0) * DS;
    for (int i = threadIdx.x; i < 8 * DS; i += 256) Bsh[i] = Bk[i];
    __syncthreads();
    float acc[8];
#pragma unroll
    for (int j = 0; j < 8; ++j) acc[j] = 0.f;
    for (int s = 0; s < DS; ++s) {
        float ws = Wk[(size_t)s * DS + t];
#pragma unroll
        for (int j = 0; j < 8; ++j) acc[j] += Bsh[j * DS + s] * ws;
    }
#pragma unroll
    for (int j = 0; j < 8; ++j)
        T1[((size_t)k * RK + (r0 + j)) * DS + t] = acc[j];
}

// ------------------------------------------- M[k][r][q] = sum_t T1[k][r][t] * B[k][q][t]
__global__ void m_kernel(const float* __restrict__ T1, const float* __restrict__ B,
                         float* __restrict__ Mm) {
    int w = blockIdx.x * 4 + (threadIdx.x >> 6);
    int lane = threadIdx.x & 63;
    int k = w / (RK * RK);
    int rem = w % (RK * RK);
    int r = rem / RK, q = rem % RK;
    const float* t1 = T1 + ((size_t)k * RK + r) * DS;
    const float* bq = B  + ((size_t)k * RK + q) * DS;
    float acc = 0.f;
    for (int t = lane; t < DS; t += 64) acc += t1[t] * bq[t];
#pragma unroll
    for (int off = 32; off > 0; off >>= 1) acc += __shfl_xor(acc, off, 64);
    if (lane == 0) Mm[w] = acc;
}

// ------------------------------------------- fused U + Wc:
// per block: stage M[k] (16KB) + 8 A-rows; compute U rows e0..e0+7 in LDS;
// then Wc[k*DL+e][d] = bf16( sum_q U[e][q] * A[k][d][q] ), A read directly
// (per-lane unit-stride rows; A is 786KB -> L2-resident, L1 caches lines).
__global__ void wcat2_kernel(const float* __restrict__ A, const float* __restrict__ Mm,
                             unsigned short* __restrict__ Wc) {
    __shared__ float Msh[RK * RK];       // 16 KB
    __shared__ float Ash[8][RK + 4];     // padded vs bank conflicts
    __shared__ float Ush[8 * RK];        // 2 KB
    const int d  = (blockIdx.x & 3) * 256 + threadIdx.x;
    const int e0 = ((blockIdx.x >> 2) & 127) * 8;
    const int k  = blockIdx.x >> 9;
    const float* Mk = Mm + (size_t)k * RK * RK;
    const float* Ak = A  + (size_t)k * DL * RK;

    for (int i = threadIdx.x; i < RK * RK / 4; i += 256)
        ((float4*)Msh)[i] = ((const float4*)Mk)[i];
    for (int i = threadIdx.x; i < 8 * RK; i += 256)
        Ash[i >> 6][i & 63] = Ak[(size_t)e0 * RK + i];
    __syncthreads();

    {   // U rows: thread -> (j = tid>>5, q0 = (tid&31)*2)
        const int j  = threadIdx.x >> 5;
        const int q0 = (threadIdx.x & 31) * 2;
        float a0 = 0.f, a1 = 0.f;
        for (int r = 0; r < RK; ++r) {
            float av = Ash[j][r];
            a0 += av * Msh[r * RK + q0];
            a1 += av * Msh[r * RK + q0 + 1];
        }
        Ush[j * RK + q0]     = a0;
        Ush[j * RK + q0 + 1] = a1;
    }
    __syncthreads();

    float acc[8];
#pragma unroll
    for (int j = 0; j < 8; ++j) acc[j] = 0.f;
    const float* Ad = Ak + (size_t)d * RK;
    for (int q4 = 0; q4 < RK / 4; ++q4) {
        float4 av = ((const float4*)Ad)[q4];
#pragma unroll
        for (int u = 0; u < 4; ++u) {
            const float a = (u == 0) ? av.x : (u == 1) ? av.y : (u == 2) ? av.z : av.w;
            const int q = q4 * 4 + u;
#pragma unroll
            for (int j = 0; j < 8; ++j) acc[j] += Ush[j * RK + q] * a;
        }
    }
#pragma unroll
    for (int j = 0; j < 8; ++j)
        Wc[((size_t)k * DL + (e0 + j)) * GK + d] = f2bf(acc[j]);
}

// ------------------------------------------- main GEMM: C[M,N] = Xb[M,K] * Wc[N,K]^T
// 256x256, 8-phase, revised per round-2 post-mortem:
//  * B-fragments held in regs across quadrant pairs (bfr0: P1/P3, bfr1: P2/P4)
//    -> 48 ds_read_b128 per wave per 2 K-tiles (was 64); P4/P8 have 0 reads.
//  * ONE barrier per phase (end). Every ds_read is consumed by a same-phase MFMA,
//    so compiler-inserted lgkmcnt forces read-completion before the barrier ->
//    next-phase stage into that slot is WAR-safe.
//  * Earlier staging (B slots free after ONE read): P1:{A1,B1}(t+1), P2:A0(t+2),
//    P4:{A1,B0}(t+2), P5:B1(t+2), P6:A0(t+3), P8:B0(t+3).
//    Waits: vmcnt(6)@P4-end (lands prevP6,prevP8,P1), vmcnt(4)@P8-end (lands
//    P2,P4,P5). Issue->wait distance >= 3 phases. Never drained in steady state.
// XOR swizzle unchanged: slot (row,cs) holds global chunk cs^(row&7); 2-way max.

#define ASL(B_, H_) (((B_) * 2 + (H_)) * 8192)
#define BSL(B_, H_) (32768 + ((B_) * 2 + (H_)) * 8192)

#define BARRIER() __builtin_amdgcn_s_barrier()
#define VWAIT(N_)                                       \
    do {                                                \
        asm volatile("s_waitcnt vmcnt(" #N_ ")");       \
        __builtin_amdgcn_sched_barrier(0);              \
    } while (0)

#define GLL(SRC, DST)                                                        \
    __builtin_amdgcn_global_load_lds(                                        \
        (const __attribute__((address_space(1))) void*)(SRC),                \
        (__attribute__((address_space(3))) void*)(DST), 16, 0, 0)

#define STG_A(H_, TR_, SL_)                                 \
    do {                                                    \
        GLL(pa##H_##0 + (TR_) * BK, shw + (SL_));           \
        GLL(pa##H_##1 + (TR_) * BK, shw + (SL_) + 4096);    \
    } while (0)

#define STG_B(H_, TR_, SL_)                                 \
    do {                                                    \
        GLL(pb##H_##0 + (TR_) * BK, shw + (SL_));           \
        GLL(pb##H_##1 + (TR_) * BK, shw + (SL_) + 4096);    \
    } while (0)

#define LDAF(B_, H_)                                                                        \
    do {                                                                                    \
        _Pragma("unroll")                                                                   \
        for (int mi = 0; mi < 4; ++mi) {                                                    \
            const int lr = lrA + mi * 16;                                                   \
            _Pragma("unroll")                                                               \
            for (int kk = 0; kk < 2; ++kk)                                                  \
                af[mi][kk] = *(const bf16x8*)(sh + ASL(B_, H_) + lr * 64 +                  \
                                              (((kk * 4 + cq) ^ (lr & 7)) * 8));            \
        }                                                                                   \
    } while (0)

#define LDBF(RG_, B_, H_)                                                                   \
    do {                                                                                    \
        _Pragma("unroll")                                                                   \
        for (int ni = 0; ni < 2; ++ni) {                                                    \
            const int lr = lrB + ni * 16;                                                   \
            _Pragma("unroll")                                                               \
            for (int kk = 0; kk < 2; ++kk)                                                  \
                RG_[ni][kk] = *(const bf16x8*)(sh + BSL(B_, H_) + lr * 64 +                 \
                                               (((kk * 4 + cq) ^ (lr & 7)) * 8));           \
        }                                                                                   \
    } while (0)

#define QUAD(MH_, NH_, BREG_)                                                               \
    do {                                                                                    \
        __builtin_amdgcn_s_setprio(1);                                                      \
        _Pragma("unroll")                                                                   \
        for (int kk = 0; kk < 2; ++kk)                                                      \
            _Pragma("unroll")                                                               \
            for (int mi = 0; mi < 4; ++mi)                                                  \
                _Pragma("unroll")                                                           \
                for (int ni = 0; ni < 2; ++ni)                                              \
                    acc[(MH_) * 4 + mi][(NH_) * 2 + ni] =                                   \
                        __builtin_amdgcn_mfma_f32_16x16x32_bf16(                            \
                            af[mi][kk], BREG_[ni][kk],                                      \
                            acc[(MH_) * 4 + mi][(NH_) * 2 + ni], 0, 0, 0);                  \
        __builtin_amdgcn_s_setprio(0);                                                      \
    } while (0)

__global__ __launch_bounds__(512, 2) void gemm_kernel(const unsigned short* __restrict__ Ag,
                                                      const unsigned short* __restrict__ Bg,
                                                      float* __restrict__ C) {
    __shared__ unsigned short sh[65536];   // 128 KiB

    const int tid  = threadIdx.x;
    const int lane = tid & 63;
    const int wave = tid >> 6;
    const int wm = wave >> 2;        // 0..1
    const int wn = wave & 3;         // 0..3

    // XCD-bijective swizzle (768 % 8 == 0)
    const int bid = blockIdx.x;
    const int wg  = (bid & 7) * ((int)gridDim.x >> 3) + (bid >> 3);
    const int bn0 = (wg % (GN / BN)) * BN;
    const int bm0 = (wg / (GN / BN)) * BM;

    // fragment read coords
    const int rr  = lane & 15;
    const int cq  = lane >> 4;           // 0..3
    const int lrA = wm * 64 + rr;
    const int lrB = wn * 32 + rr;

    // per-lane source offset within a 128x64 half (pre-inverse-swizzled)
    const int srow = tid >> 3;           // 0..63
    const int scs  = tid & 7;
    const int soff = srow * GK + ((scs ^ (srow & 7)) * 8);

    const unsigned short* pa00 = Ag + (size_t)bm0 * GK + soff;
    const unsigned short* pa01 = pa00 + (size_t)64 * GK;
    const unsigned short* pa10 = pa00 + (size_t)128 * GK;
    const unsigned short* pa11 = pa00 + (size_t)192 * GK;
    const unsigned short* pb00 = Bg + (size_t)bn0 * GK + soff;
    const unsigned short* pb01 = pb00 + (size_t)64 * GK;
    const unsigned short* pb10 = pb00 + (size_t)128 * GK;
    const unsigned short* pb11 = pb00 + (size_t)192 * GK;

    unsigned short* const shw = sh + wave * 512;

    f32x4 acc[8][4];
#pragma unroll
    for (int i = 0; i < 8; ++i)
#pragma unroll
        for (int j = 0; j < 4; ++j) {
            f32x4 z = {0.f, 0.f, 0.f, 0.f};
            acc[i][j] = z;
        }
    bf16x8 af[4][2], bfr0[2][2], bfr1[2][2];

    // Prologue: tile0 all 4 halves + tile1 A0,B0 (the latter stay in flight)
    STG_A(0, 0, ASL(0, 0));
    STG_B(0, 0, BSL(0, 0));
    STG_A(1, 0, ASL(0, 1));
    STG_B(1, 0, BSL(0, 1));
    STG_A(0, 1, ASL(1, 0));
    STG_B(0, 1, BSL(1, 0));
    VWAIT(4);
    BARRIER();

#pragma unroll 1
    for (int ti = 0; ti < NTK - 2; ti += 2) {
        // P1: read b0.A0 -> af, b0.B0 -> bfr0; stage (t+1)A1,(t+1)B1 -> buf1
        LDAF(0, 0); LDBF(bfr0, 0, 0);
        STG_A(1, 1, ASL(1, 1)); STG_B(1, 1, BSL(1, 1));
        QUAD(0, 0, bfr0);
        BARRIER();
        // P2: read b0.B1 -> bfr1; stage (t+2)A0 -> b0.A0 (freed P1)
        LDBF(bfr1, 0, 1);
        STG_A(0, 2, ASL(0, 0));
        QUAD(0, 1, bfr1);
        BARRIER();
        // P3: read b0.A1 -> af (reuse bfr0)
        LDAF(0, 1);
        QUAD(1, 0, bfr0);
        BARRIER();
        // P4: no reads (af x bfr1); stage (t+2)A1 -> b0.A1 (freed P3),
        //     (t+2)B0 -> b0.B0 (freed P1); counted wait vmcnt(6)
        STG_A(1, 2, ASL(0, 1)); STG_B(0, 2, BSL(0, 0));
        QUAD(1, 1, bfr1);
        VWAIT(6);
        BARRIER();
        // P5: read b1.A0 -> af, b1.B0 -> bfr0; stage (t+2)B1 -> b0.B1 (freed P2)
        LDAF(1, 0); LDBF(bfr0, 1, 0);
        STG_B(1, 2, BSL(0, 1));
        QUAD(0, 0, bfr0);
        BARRIER();
        // P6: read b1.B1 -> bfr1; stage (t+3)A0 -> b1.A0 (freed P5)
        LDBF(bfr1, 1, 1);
        STG_A(0, 3, ASL(1, 0));
        QUAD(0, 1, bfr1);
        BARRIER();
        // P7: read b1.A1 -> af
        LDAF(1, 1);
        QUAD(1, 0, bfr0);
        BARRIER();
        // P8: no reads; stage (t+3)B0 -> b1.B0 (freed P5); counted wait vmcnt(4)
        STG_B(0, 3, BSL(1, 0));
        QUAD(1, 1, bfr1);
        VWAIT(4);
        BARRIER();
        pa00 += 2 * BK; pa01 += 2 * BK; pa10 += 2 * BK; pa11 += 2 * BK;
        pb00 += 2 * BK; pb01 += 2 * BK; pb10 += 2 * BK; pb11 += 2 * BK;
    }

    // Tail (tiles NTK-2, NTK-1): only (t+1)A1/B1 still staged; full drain at P4.
    LDAF(0, 0); LDBF(bfr0, 0, 0);
    STG_A(1, 1, ASL(1, 1)); STG_B(1, 1, BSL(1, 1));
    QUAD(0, 0, bfr0);
    BARRIER();
    LDBF(bfr1, 0, 1);
    QUAD(0, 1, bfr1);
    BARRIER();
    LDAF(0, 1);
    QUAD(1, 0, bfr0);
    BARRIER();
    QUAD(1, 1, bfr1);
    VWAIT(0);
    BARRIER();
    LDAF(1, 0); LDBF(bfr0, 1, 0);
    QUAD(0, 0, bfr0);
    BARRIER();
    LDBF(bfr1, 1, 1);
    QUAD(0, 1, bfr1);
    BARRIER();
    LDAF(1, 1);
    QUAD(1, 0, bfr0);
    BARRIER();
    QUAD(1, 1, bfr1);

    // epilogue: D layout col=lane&15, row=(lane>>4)*4+reg
    const int cn  = lane & 15;
    const int rg4 = (lane >> 4) * 4;
#pragma unroll
    for (int m = 0; m < 8; ++m) {
        const int mh = m >> 2, mi = m & 3;
        const int row0 = bm0 + mh * 128 + wm * 64 + mi * 16 + rg4;
#pragma unroll
        for (int n = 0; n < 4; ++n) {
            const int nh = n >> 1, ni = n & 1;
            const int col = bn0 + nh * 128 + wn * 32 + ni * 16 + cn;
#pragma unroll
            for (int r = 0; r < 4; ++r)
                C[(size_t)(row0 + r) * GN + col] = acc[m][n][r];
        }
    }
}

extern "C" void kernel_launch(void* const* d_in, const int* in_sizes, int n_in,
                              void* d_out, int out_size, void* d_ws, size_t ws_size,
                              hipStream_t stream) {
    const float* x   = (const float*)d_in[0];
    const float* Wsm = (const float*)d_in[1];
    const float* A   = (const float*)d_in[2];
    const float* B   = (const float*)d_in[3];
    float* out = (float*)d_out;
    char* ws = (char*)d_ws;

    unsigned short* xb = (unsigned short*)(ws);                       // 33,554,432 B
    unsigned short* Wc = (unsigned short*)(ws + 33554432);            //  6,291,456 B
    float* T1          = (float*)(ws + 39845888);                     //    589,824 B
    float* Mm          = (float*)(ws + 40435712);                     //     49,152 B

    cvt_kernel<<<GM * GK / 4 / 256, 256, 0, stream>>>(x, xb, GM * GK / 4);
    t1_kernel<<<dim3(3, 8, 3), 256, 0, stream>>>(Wsm, B, T1);
    m_kernel<<<3 * RK * RK / 4, 256, 0, stream>>>(T1, B, Mm);
    wcat2_kernel<<<1536, 256, 0, stream>>>(A, Mm, Wc);
    gemm_kernel<<<(GM / BM) * (GN / BN), 512, 0, stream>>>(xb, Wc, out);
}